// Round 11
// baseline (330.893 us; speedup 1.0000x reference)
//
#include <hip/hip_runtime.h>

#define BDIM 4
#define LDIM 4096
#define DDIM 1024
#define KTAPS 128
#define LCHUNK 64

typedef __attribute__((ext_vector_type(8))) _Float16 f16x8;
typedef __attribute__((ext_vector_type(16))) float f32x16;

// ---------------------------------------------------------------------------
// fp16 helpers
// ---------------------------------------------------------------------------
__device__ __forceinline__ float f16_to_f(ushort h) {
    return (float)__builtin_bit_cast(_Float16, h);
}
__device__ __forceinline__ ushort f_to_f16(float f) {
    return __builtin_bit_cast(ushort, (_Float16)f);  // v_cvt_f16_f32, RNE
}

__device__ __forceinline__ void load_lds16(const ushort* g, ushort* l) {
    __builtin_amdgcn_global_load_lds(
        (const __attribute__((address_space(1))) void*)g,
        (__attribute__((address_space(3))) void*)l, 16, 0, 0);
}

// granule swizzle for LDS row r (4 octets of 16B per 64B row); period-16 in r
#define NSWZ(r) ((((r) & 3) ^ (((r) >> 2) & 3)))

// ---------------------------------------------------------------------------
// fp32 -> fp16 convert (vectorized, grid-stride) — weights only now
// ---------------------------------------------------------------------------
__global__ __launch_bounds__(256) void to_f16(const float* __restrict__ in,
                                              ushort* __restrict__ out, int n4) {
    for (int i = blockIdx.x * 256 + threadIdx.x; i < n4; i += gridDim.x * 256) {
        const float4 v = *(const float4*)&in[(size_t)i * 4];
        ushort4 h;
        h.x = f_to_f16(v.x);
        h.y = f_to_f16(v.y);
        h.z = f_to_f16(v.z);
        h.w = f_to_f16(v.w);
        *(ushort4*)&out[(size_t)i * 4] = h;
    }
}

// ---------------------------------------------------------------------------
// GEMM1 with fused x-convert: A is fp32 [M,K], converted to f16 during
// reg-staging (forced reg-stage -> T14 split applies: A-loads for tile t+1
// issue before the raw barrier; s_waitcnt vmcnt(4) drains only B's two
// global_load_lds, so the 4 A-loads ride through the full compute window).
// Otherwise exact r8 structure: 128x128, BK=32, single-buffer, 32x32x16 MFMA.
// B [N,K] f16 row-major. C f16.
// ---------------------------------------------------------------------------
__global__ __launch_bounds__(256) void gemm1_xa(const float* __restrict__ X,
                                                const ushort* __restrict__ B,
                                                ushort* __restrict__ C, int ldc, int Kc) {
    __shared__ ushort As[128 * 32];
    __shared__ ushort Bs[128 * 32];

    const int tid = threadIdx.x;

    // bijective XCD swizzle (nwg % 8 == 0)
    const int gx = gridDim.x;
    const int nwg = gx * gridDim.y;
    const int orig = blockIdx.y * gx + blockIdx.x;
    const int q8 = nwg >> 3;
    const int tile = (orig & 7) * q8 + (orig >> 3);
    const int m0 = (tile / gx) * 128;
    const int n0 = (tile % gx) * 128;

    // staging: thread t -> LDS rows t>>2 and +64, octet t&3; inverse-swizzled src
    const int ra = tid >> 2;
    const int ga = tid & 3;
    const int gs = (ga ^ NSWZ(ra)) * 8;  // element offset (same count in f32/f16)

    const float* xs0 = X + (size_t)(m0 + ra) * Kc + gs;
    const float* xs1 = X + (size_t)(m0 + 64 + ra) * Kc + gs;
    const ushort* srcB0 = B + (size_t)(n0 + ra) * Kc + gs;
    const ushort* srcB1 = B + (size_t)(n0 + 64 + ra) * Kc + gs;

    const int lane = tid & 63;
    const int w = tid >> 6;
    const int wr = w >> 1, wc = w & 1;
    const int l31 = lane & 31;
    const int hi = lane >> 5;
    const int nsw = NSWZ(l31 & 15);
    const int arow = wr * 64 + l31;
    const int brow = wc * 64 + l31;
    const int NT = Kc >> 5;

    f32x16 acc[2][2] = {};
    float4 a0lo, a0hi, a1lo, a1hi;  // A-staging regs (one K-tile octet pair)

    auto ALOAD = [&](const int kt) {
        const float* p0 = xs0 + kt * 32;
        const float* p1 = xs1 + kt * 32;
        a0lo = *(const float4*)p0;
        a0hi = *(const float4*)(p0 + 4);
        a1lo = *(const float4*)p1;
        a1hi = *(const float4*)(p1 + 4);
    };
    auto PACK = [](const float4 u, const float4 v) {
        f16x8 r;
        r[0] = (_Float16)u.x; r[1] = (_Float16)u.y;
        r[2] = (_Float16)u.z; r[3] = (_Float16)u.w;
        r[4] = (_Float16)v.x; r[5] = (_Float16)v.y;
        r[6] = (_Float16)v.z; r[7] = (_Float16)v.w;
        return r;
    };

    ALOAD(0);
    for (int t = 0; t < NT; ++t) {
        __syncthreads();  // prev ds_reads done (also drains A(t) regs - needed next anyway)
        load_lds16(srcB0 + t * 32, &Bs[tid * 8]);
        load_lds16(srcB1 + t * 32, &Bs[(tid + 256) * 8]);
        *(f16x8*)&As[tid * 8] = PACK(a0lo, a0hi);          // cvt+ds_write (compiler
        *(f16x8*)&As[(tid + 256) * 8] = PACK(a1lo, a1hi);  //  waits A regs)
        if (t + 1 < NT) {
            ALOAD(t + 1);  // 4 reg-loads in flight through barrier + compute
            asm volatile("s_waitcnt vmcnt(4) lgkmcnt(0)" ::: "memory");
        } else {
            asm volatile("s_waitcnt vmcnt(0) lgkmcnt(0)" ::: "memory");
        }
        __builtin_amdgcn_sched_barrier(0);
        __builtin_amdgcn_s_barrier();

        f16x8 a[2][2], b[2][2];
#pragma unroll
        for (int rb = 0; rb < 2; ++rb)
#pragma unroll
            for (int kh = 0; kh < 2; ++kh)
                a[rb][kh] = *(const f16x8*)&As[(arow + rb * 32) * 32 +
                                              (((2 * kh + hi) ^ nsw) * 8)];
#pragma unroll
        for (int cb = 0; cb < 2; ++cb)
#pragma unroll
            for (int kh = 0; kh < 2; ++kh)
                b[cb][kh] = *(const f16x8*)&Bs[(brow + cb * 32) * 32 +
                                              (((2 * kh + hi) ^ nsw) * 8)];
#pragma unroll
        for (int rb = 0; rb < 2; ++rb)
#pragma unroll
            for (int cb = 0; cb < 2; ++cb) {
                acc[rb][cb] = __builtin_amdgcn_mfma_f32_32x32x16_f16(
                    a[rb][0], b[cb][0], acc[rb][cb], 0, 0, 0);
                acc[rb][cb] = __builtin_amdgcn_mfma_f32_32x32x16_f16(
                    a[rb][1], b[cb][1], acc[rb][cb], 0, 0, 0);
            }
    }

    // C/D (m74/m101): col = lane&31, row = (q&3) + 8*(q>>2) + 4*hi
#pragma unroll
    for (int rb = 0; rb < 2; ++rb)
#pragma unroll
        for (int cb = 0; cb < 2; ++cb) {
            const int colb = n0 + wc * 64 + cb * 32 + l31;
            const int rowb = m0 + wr * 64 + rb * 32 + 4 * hi;
#pragma unroll
            for (int q = 0; q < 16; ++q) {
                const int row = rowb + (q & 3) + 8 * (q >> 2);
                C[(size_t)row * ldc + colb] = f_to_f16(acc[rb][cb][q]);
            }
        }
}

// ---------------------------------------------------------------------------
// fp16 NT GEMM, exact r8 structure (measured best: 137.6us GEMM1-shape):
// 128x128, BK=32, single 16KB buffer, two __syncthreads per iter, 32x32x16.
// OBF=1 -> f16 C, OBF=0 -> f32 C.  (Used for GEMM2.)
// ---------------------------------------------------------------------------
template <int OBF>
__global__ __launch_bounds__(256) void gemm_f16(const ushort* __restrict__ A,
                                                const ushort* __restrict__ B,
                                                void* __restrict__ Cp, int ldc, int Kc) {
    __shared__ ushort As[128 * 32];
    __shared__ ushort Bs[128 * 32];

    const int tid = threadIdx.x;

    const int gx = gridDim.x;
    const int nwg = gx * gridDim.y;
    const int orig = blockIdx.y * gx + blockIdx.x;
    const int q8 = nwg >> 3;
    const int tile = (orig & 7) * q8 + (orig >> 3);
    const int m0 = (tile / gx) * 128;
    const int n0 = (tile % gx) * 128;

    const int ra = tid >> 2;
    const int ga = tid & 3;
    const int gs = (ga ^ NSWZ(ra)) * 8;

    const ushort* srcA0 = A + (size_t)(m0 + ra) * Kc + gs;
    const ushort* srcA1 = A + (size_t)(m0 + 64 + ra) * Kc + gs;
    const ushort* srcB0 = B + (size_t)(n0 + ra) * Kc + gs;
    const ushort* srcB1 = B + (size_t)(n0 + 64 + ra) * Kc + gs;

    const int lane = tid & 63;
    const int w = tid >> 6;
    const int wr = w >> 1, wc = w & 1;
    const int l31 = lane & 31;
    const int hi = lane >> 5;
    const int nsw = NSWZ(l31 & 15);
    const int arow = wr * 64 + l31;
    const int brow = wc * 64 + l31;

    f32x16 acc[2][2] = {};

    for (int kc = 0; kc < Kc; kc += 32) {
        __syncthreads();
        load_lds16(srcA0, &As[tid * 8]);
        load_lds16(srcA1, &As[(tid + 256) * 8]);
        load_lds16(srcB0, &Bs[tid * 8]);
        load_lds16(srcB1, &Bs[(tid + 256) * 8]);
        srcA0 += 32; srcA1 += 32; srcB0 += 32; srcB1 += 32;
        __syncthreads();

        f16x8 a[2][2], b[2][2];
#pragma unroll
        for (int rb = 0; rb < 2; ++rb)
#pragma unroll
            for (int kh = 0; kh < 2; ++kh)
                a[rb][kh] = *(const f16x8*)&As[(arow + rb * 32) * 32 +
                                              (((2 * kh + hi) ^ nsw) * 8)];
#pragma unroll
        for (int cb = 0; cb < 2; ++cb)
#pragma unroll
            for (int kh = 0; kh < 2; ++kh)
                b[cb][kh] = *(const f16x8*)&Bs[(brow + cb * 32) * 32 +
                                              (((2 * kh + hi) ^ nsw) * 8)];
#pragma unroll
        for (int rb = 0; rb < 2; ++rb)
#pragma unroll
            for (int cb = 0; cb < 2; ++cb) {
                acc[rb][cb] = __builtin_amdgcn_mfma_f32_32x32x16_f16(
                    a[rb][0], b[cb][0], acc[rb][cb], 0, 0, 0);
                acc[rb][cb] = __builtin_amdgcn_mfma_f32_32x32x16_f16(
                    a[rb][1], b[cb][1], acc[rb][cb], 0, 0, 0);
            }
    }

#pragma unroll
    for (int rb = 0; rb < 2; ++rb)
#pragma unroll
        for (int cb = 0; cb < 2; ++cb) {
            const int colb = n0 + wc * 64 + cb * 32 + l31;
            const int rowb = m0 + wr * 64 + rb * 32 + 4 * hi;
#pragma unroll
            for (int q = 0; q < 16; ++q) {
                const int row = rowb + (q & 3) + 8 * (q >> 2);
                if (OBF) {
                    ((ushort*)Cp)[(size_t)row * ldc + colb] = f_to_f16(acc[rb][cb][q]);
                } else {
                    ((float*)Cp)[(size_t)row * ldc + colb] = acc[rb][cb][q];
                }
            }
        }
}

// ---------------------------------------------------------------------------
// conv + gate, d-pair vectorized: each thread owns 2 channels via uint loads
// (wave reads 256B contiguous per row = full cache lines; halves inst count).
// 128 threads, grid (64,4,4) = 1024 blocks (proven block count / chain len).
// decay geometric => exact IIR: res = r*res + s[l] - decay128*s[l-128].
// ---------------------------------------------------------------------------
__device__ __forceinline__ float2 up2(uint u) {
    return make_float2(f16_to_f((ushort)(u & 0xffff)), f16_to_f((ushort)(u >> 16)));
}

__global__ __launch_bounds__(128) void conv_gate_f16(const ushort* __restrict__ qkvh,
                                                     const float* __restrict__ decay,
                                                     ushort* __restrict__ gh) {
    __shared__ float sdec[KTAPS];
    sdec[threadIdx.x] = decay[threadIdx.x];  // 128 threads == KTAPS
    __syncthreads();

    const int dp = blockIdx.y * 128 + threadIdx.x;  // d-pair 0..511
    const int b = blockIdx.z;
    const int l0 = blockIdx.x * LCHUNK;

    const float r = sdec[1];
    const float dlast = r * sdec[KTAPS - 1];  // decay[128]
    const int rsu = 3 * DDIM / 2;             // qkv row stride in uints
    const int gsu = DDIM / 2;                 // gh row stride in uints

    const uint* basep = (const uint*)(qkvh + (size_t)b * LDIM * 3 * DDIM);
    const uint* qc = basep + dp;
    const uint* kc = basep + DDIM / 2 + dp;
    const uint* vc = basep + DDIM + dp;
    uint* g0 = (uint*)(gh + (size_t)b * LDIM * DDIM) + dp;

    float res0 = 0.f, res1 = 0.f;
    int lstart;
    if (l0 == 0) {
        lstart = 0;
    } else {
        const int tmax = (l0 < KTAPS - 1) ? l0 : (KTAPS - 1);
#pragma unroll 4
        for (int t = 0; t <= tmax; ++t) {
            const size_t off = (size_t)(l0 - t) * rsu;
            const float2 kk = up2(kc[off]), vv = up2(vc[off]);
            res0 += sdec[t] * kk.x * vv.x;
            res1 += sdec[t] * kk.y * vv.y;
        }
        const float2 qq = up2(qc[(size_t)l0 * rsu]);
        g0[(size_t)l0 * gsu] = (uint)f_to_f16(qq.x * res0) |
                               ((uint)f_to_f16(qq.y * res1) << 16);
        lstart = l0 + 1;
    }

    for (int l = lstart; l < l0 + LCHUNK; ++l) {
        const size_t off = (size_t)l * rsu;
        const float2 kk = up2(kc[off]), vv = up2(vc[off]);
        const float s0 = kk.x * vv.x, s1 = kk.y * vv.y;
        if (l == 0) {
            res0 = sdec[0] * s0;
            res1 = sdec[0] * s1;
        } else {
            float sub0 = 0.f, sub1 = 0.f;
            if (l >= KTAPS) {
                const size_t o2 = (size_t)(l - KTAPS) * rsu;
                const float2 k2 = up2(kc[o2]), v2 = up2(vc[o2]);
                sub0 = dlast * k2.x * v2.x;
                sub1 = dlast * k2.y * v2.y;
            }
            res0 = r * res0 + s0 - sub0;
            res1 = r * res1 + s1 - sub1;
        }
        const float2 qq = up2(qc[off]);
        g0[(size_t)l * gsu] = (uint)f_to_f16(qq.x * res0) |
                              ((uint)f_to_f16(qq.y * res1) << 16);
    }
}

// ---------------------------------------------------------------------------
// Memory plan (ws proven >= 192MB; uses 136MB):
//   ws[  0.. 96MB) qkvh  f16 [16384,3072]  GEMM1 out
//   ws[ 96..128MB) gh    f16 [16384,1024]  conv out = GEMM2 A
//   ws[128..134MB) wqkvh f16 [3072,1024]   GEMM1 B
//   ws[134..136MB) wouth f16 [1024,1024]   GEMM2 B
//   (x is read fp32 directly by GEMM1 — no xh buffer, no x convert pass)
// ---------------------------------------------------------------------------
extern "C" void kernel_launch(void* const* d_in, const int* in_sizes, int n_in,
                              void* d_out, int out_size, void* d_ws, size_t ws_size,
                              hipStream_t stream) {
    const float* x = (const float*)d_in[0];
    const float* Wqkv = (const float*)d_in[1];
    const float* Wout = (const float*)d_in[2];
    const float* decay = (const float*)d_in[3];

    const int M = BDIM * LDIM;  // 16384
    const size_t MB = 1024 * 1024;

    ushort* qkvh = (ushort*)d_ws;
    ushort* gh = (ushort*)((char*)d_ws + 96 * MB);
    ushort* wqkvh = (ushort*)((char*)d_ws + 128 * MB);
    ushort* wouth = (ushort*)((char*)d_ws + 134 * MB);

    // weight converts only (x is consumed fp32 by gemm1_xa)
    to_f16<<<512, 256, 0, stream>>>(Wqkv, wqkvh, 3 * DDIM * DDIM / 4);
    to_f16<<<256, 256, 0, stream>>>(Wout, wouth, DDIM * DDIM / 4);

    // GEMM1 (fused x-convert): qkvh = f16(x) @ wqkvh^T, f16 out
    dim3 g1(3 * DDIM / 128, M / 128);  // 24 x 128 = 3072 wgs (%8==0)
    gemm1_xa<<<g1, 256, 0, stream>>>(x, wqkvh, qkvh, 3 * DDIM, DDIM);

    // conv + gate -> gh (d-pair vectorized)
    dim3 g2(LDIM / LCHUNK, DDIM / 256, BDIM);  // 64 x 4 x 4 = 1024 blocks
    conv_gate_f16<<<g2, 128, 0, stream>>>(qkvh, decay, gh);

    // GEMM2: out = gh @ wouth^T, f32 out (exact r8 GEMM)
    dim3 g3(DDIM / 128, M / 128);  // 8 x 128 = 1024 wgs (%8==0)
    gemm_f16<0><<<g3, 256, 0, stream>>>(gh, wouth, d_out, DDIM, DDIM);
}

// Round 12
// 258.161 us; speedup vs baseline: 1.2817x; 1.2817x over previous
//
#include <hip/hip_runtime.h>

#define BDIM 4
#define LDIM 4096
#define DDIM 1024
#define KTAPS 128
#define LCHUNK 64

typedef __attribute__((ext_vector_type(8))) _Float16 f16x8;
typedef __attribute__((ext_vector_type(16))) float f32x16;

// ---------------------------------------------------------------------------
// fp16 helpers
// ---------------------------------------------------------------------------
__device__ __forceinline__ float f16_to_f(ushort h) {
    return (float)__builtin_bit_cast(_Float16, h);
}
__device__ __forceinline__ ushort f_to_f16(float f) {
    return __builtin_bit_cast(ushort, (_Float16)f);  // v_cvt_f16_f32, RNE
}

__device__ __forceinline__ void load_lds16(const ushort* g, ushort* l) {
    __builtin_amdgcn_global_load_lds(
        (const __attribute__((address_space(1))) void*)g,
        (__attribute__((address_space(3))) void*)l, 16, 0, 0);
}

// granule swizzle for LDS row r (4 octets of 16B per 64B row); period-16 in r
#define NSWZ(r) ((((r) & 3) ^ (((r) >> 2) & 3)))

// ---------------------------------------------------------------------------
// fused fp32 -> fp16 convert for all three inputs (one launch) — r8 proven
// ---------------------------------------------------------------------------
#define NX4 (BDIM * LDIM * DDIM / 4)        // 4194304
#define NQ4 (3 * DDIM * DDIM / 4)           // 786432
#define NO4 (DDIM * DDIM / 4)               // 262144
__global__ __launch_bounds__(256) void to_f16_all(const float* __restrict__ x,
                                                  const float* __restrict__ wq,
                                                  const float* __restrict__ wo,
                                                  ushort* __restrict__ xh,
                                                  ushort* __restrict__ wqh,
                                                  ushort* __restrict__ woh) {
    const int ntot = NX4 + NQ4 + NO4;
    for (int i = blockIdx.x * 256 + threadIdx.x; i < ntot; i += gridDim.x * 256) {
        const float* src;
        ushort* dst;
        int j = i;
        if (j < NX4) {
            src = x; dst = xh;
        } else if (j < NX4 + NQ4) {
            j -= NX4; src = wq; dst = wqh;
        } else {
            j -= NX4 + NQ4; src = wo; dst = woh;
        }
        const float4 v = *(const float4*)&src[(size_t)j * 4];
        ushort4 h;
        h.x = f_to_f16(v.x);
        h.y = f_to_f16(v.y);
        h.z = f_to_f16(v.z);
        h.w = f_to_f16(v.w);
        *(ushort4*)&dst[(size_t)j * 4] = h;
    }
}

// ---------------------------------------------------------------------------
// fp16 NT GEMM — exact r8 structure (measured best across r4-r11 variants):
// 128x128 tile, BK=32, 4 waves, single 16KB buffer, two __syncthreads/iter,
// 32x32x16 MFMA, global_load_lds staging w/ pre-swizzled source octets.
// A/B frag map: lane l -> row/col = l&31, k-octet = l>>5;
// C/D map (m74/m101): col = lane&31, row = (q&3)+8*(q>>2)+4*(lane>>5).
// OBF=1 -> f16 C, OBF=0 -> f32 C. XCD-aware tile swizzle.
// ---------------------------------------------------------------------------
template <int OBF>
__global__ __launch_bounds__(256) void gemm_f16(const ushort* __restrict__ A,
                                                const ushort* __restrict__ B,
                                                void* __restrict__ Cp, int ldc, int Kc) {
    __shared__ ushort As[128 * 32];
    __shared__ ushort Bs[128 * 32];

    const int tid = threadIdx.x;

    const int gx = gridDim.x;
    const int nwg = gx * gridDim.y;
    const int orig = blockIdx.y * gx + blockIdx.x;
    const int q8 = nwg >> 3;
    const int tile = (orig & 7) * q8 + (orig >> 3);
    const int m0 = (tile / gx) * 128;
    const int n0 = (tile % gx) * 128;

    const int ra = tid >> 2;
    const int ga = tid & 3;
    const int gs = (ga ^ NSWZ(ra)) * 8;

    const ushort* srcA0 = A + (size_t)(m0 + ra) * Kc + gs;
    const ushort* srcA1 = A + (size_t)(m0 + 64 + ra) * Kc + gs;
    const ushort* srcB0 = B + (size_t)(n0 + ra) * Kc + gs;
    const ushort* srcB1 = B + (size_t)(n0 + 64 + ra) * Kc + gs;

    const int lane = tid & 63;
    const int w = tid >> 6;
    const int wr = w >> 1, wc = w & 1;
    const int l31 = lane & 31;
    const int hi = lane >> 5;
    const int nsw = NSWZ(l31 & 15);
    const int arow = wr * 64 + l31;
    const int brow = wc * 64 + l31;

    f32x16 acc[2][2] = {};

    for (int kc = 0; kc < Kc; kc += 32) {
        __syncthreads();
        load_lds16(srcA0, &As[tid * 8]);
        load_lds16(srcA1, &As[(tid + 256) * 8]);
        load_lds16(srcB0, &Bs[tid * 8]);
        load_lds16(srcB1, &Bs[(tid + 256) * 8]);
        srcA0 += 32; srcA1 += 32; srcB0 += 32; srcB1 += 32;
        __syncthreads();

        f16x8 a[2][2], b[2][2];
#pragma unroll
        for (int rb = 0; rb < 2; ++rb)
#pragma unroll
            for (int kh = 0; kh < 2; ++kh)
                a[rb][kh] = *(const f16x8*)&As[(arow + rb * 32) * 32 +
                                              (((2 * kh + hi) ^ nsw) * 8)];
#pragma unroll
        for (int cb = 0; cb < 2; ++cb)
#pragma unroll
            for (int kh = 0; kh < 2; ++kh)
                b[cb][kh] = *(const f16x8*)&Bs[(brow + cb * 32) * 32 +
                                              (((2 * kh + hi) ^ nsw) * 8)];
#pragma unroll
        for (int rb = 0; rb < 2; ++rb)
#pragma unroll
            for (int cb = 0; cb < 2; ++cb) {
                acc[rb][cb] = __builtin_amdgcn_mfma_f32_32x32x16_f16(
                    a[rb][0], b[cb][0], acc[rb][cb], 0, 0, 0);
                acc[rb][cb] = __builtin_amdgcn_mfma_f32_32x32x16_f16(
                    a[rb][1], b[cb][1], acc[rb][cb], 0, 0, 0);
            }
    }

#pragma unroll
    for (int rb = 0; rb < 2; ++rb)
#pragma unroll
        for (int cb = 0; cb < 2; ++cb) {
            const int colb = n0 + wc * 64 + cb * 32 + l31;
            const int rowb = m0 + wr * 64 + rb * 32 + 4 * hi;
#pragma unroll
            for (int q = 0; q < 16; ++q) {
                const int row = rowb + (q & 3) + 8 * (q >> 2);
                if (OBF) {
                    ((ushort*)Cp)[(size_t)row * ldc + colb] = f_to_f16(acc[rb][cb][q]);
                } else {
                    ((float*)Cp)[(size_t)row * ldc + colb] = acc[rb][cb][q];
                }
            }
        }
}

// ---------------------------------------------------------------------------
// conv + gate, channel-pair vectorized at full block size: 256 threads each
// own 2 channels (uint loads/stores -> wave reads 256B/row), grid (64,2,4).
// Serial chain length unchanged (LCHUNK=64, proven). Inner loop de-branched:
// chunk 0 seeds at l=0 and never subtracts; chunks >=1 seed with tap sum;
// subtract starts exactly at l>=128.
// decay geometric => exact IIR: res = r*res + s[l] - decay128*s[l-128].
// ---------------------------------------------------------------------------
__device__ __forceinline__ float2 up2(uint u) {
    return make_float2(f16_to_f((ushort)(u & 0xffff)), f16_to_f((ushort)(u >> 16)));
}

__global__ __launch_bounds__(256) void conv_gate_f16(const ushort* __restrict__ qkvh,
                                                     const float* __restrict__ decay,
                                                     ushort* __restrict__ gh) {
    __shared__ float sdec[KTAPS];
    if (threadIdx.x < KTAPS) sdec[threadIdx.x] = decay[threadIdx.x];
    __syncthreads();

    const int dp = blockIdx.y * 256 + threadIdx.x;  // d-pair 0..511
    const int b = blockIdx.z;
    const int l0 = blockIdx.x * LCHUNK;

    const float r = sdec[1];
    const float dlast = r * sdec[KTAPS - 1];  // decay[128]
    const int rsu = 3 * DDIM / 2;             // qkv row stride in uints
    const int gsu = DDIM / 2;                 // gh row stride in uints

    const uint* basep = (const uint*)(qkvh + (size_t)b * LDIM * 3 * DDIM);
    const uint* qc = basep + dp;
    const uint* kc = basep + DDIM / 2 + dp;
    const uint* vc = basep + DDIM + dp;
    uint* g0 = (uint*)(gh + (size_t)b * LDIM * DDIM) + dp;

    float res0 = 0.f, res1 = 0.f;

    if (l0 == 0) {
        // chunk 0: l = 0..63, no subtract ever (l < 128)
        for (int l = 0; l < LCHUNK; ++l) {
            const size_t off = (size_t)l * rsu;
            const float2 kk = up2(kc[off]), vv = up2(vc[off]);
            res0 = r * res0 + kk.x * vv.x;
            res1 = r * res1 + kk.y * vv.y;
            const float2 qq = up2(qc[off]);
            g0[(size_t)l * gsu] = (uint)f_to_f16(qq.x * res0) |
                                  ((uint)f_to_f16(qq.y * res1) << 16);
        }
        return;
    }

    // seed: res[l0] = sum_{t=0}^{min(127,l0)} decay[t] * src[l0-t]
    const int tmax = (l0 < KTAPS - 1) ? l0 : (KTAPS - 1);
#pragma unroll 4
    for (int t = 0; t <= tmax; ++t) {
        const size_t off = (size_t)(l0 - t) * rsu;
        const float2 kk = up2(kc[off]), vv = up2(vc[off]);
        res0 += sdec[t] * kk.x * vv.x;
        res1 += sdec[t] * kk.y * vv.y;
    }
    {
        const float2 qq = up2(qc[(size_t)l0 * rsu]);
        g0[(size_t)l0 * gsu] = (uint)f_to_f16(qq.x * res0) |
                               ((uint)f_to_f16(qq.y * res1) << 16);
    }

    // body: subtract active only for l >= 128; split the l-range accordingly
    const int lend = l0 + LCHUNK;
    const int nosubEnd = (lend < KTAPS) ? lend : KTAPS;
    for (int l = l0 + 1; l < nosubEnd; ++l) {
        const size_t off = (size_t)l * rsu;
        const float2 kk = up2(kc[off]), vv = up2(vc[off]);
        res0 = r * res0 + kk.x * vv.x;
        res1 = r * res1 + kk.y * vv.y;
        const float2 qq = up2(qc[off]);
        g0[(size_t)l * gsu] = (uint)f_to_f16(qq.x * res0) |
                              ((uint)f_to_f16(qq.y * res1) << 16);
    }
    const int subStart = (l0 + 1 > KTAPS) ? l0 + 1 : KTAPS;
    for (int l = subStart; l < lend; ++l) {
        const size_t off = (size_t)l * rsu;
        const size_t o2 = (size_t)(l - KTAPS) * rsu;
        const float2 kk = up2(kc[off]), vv = up2(vc[off]);
        const float2 k2 = up2(kc[o2]), v2 = up2(vc[o2]);
        res0 = r * res0 + kk.x * vv.x - dlast * k2.x * v2.x;
        res1 = r * res1 + kk.y * vv.y - dlast * k2.y * v2.y;
        const float2 qq = up2(qc[off]);
        g0[(size_t)l * gsu] = (uint)f_to_f16(qq.x * res0) |
                              ((uint)f_to_f16(qq.y * res1) << 16);
    }
}

// ---------------------------------------------------------------------------
// Memory plan (ws proven >= 192MB; uses 168MB):
//   ws[  0.. 96MB) qkvh  f16 [16384,3072]  GEMM1 out
//   ws[ 96..128MB) gh    f16 [16384,1024]  conv out = GEMM2 A
//   ws[128..160MB) xh    f16 [16384,1024]  GEMM1 A
//   ws[160..166MB) wqkvh f16 [3072,1024]   GEMM1 B
//   ws[166..168MB) wouth f16 [1024,1024]   GEMM2 B
// ---------------------------------------------------------------------------
extern "C" void kernel_launch(void* const* d_in, const int* in_sizes, int n_in,
                              void* d_out, int out_size, void* d_ws, size_t ws_size,
                              hipStream_t stream) {
    const float* x = (const float*)d_in[0];
    const float* Wqkv = (const float*)d_in[1];
    const float* Wout = (const float*)d_in[2];
    const float* decay = (const float*)d_in[3];

    const int M = BDIM * LDIM;  // 16384
    const size_t MB = 1024 * 1024;

    ushort* qkvh = (ushort*)d_ws;
    ushort* gh = (ushort*)((char*)d_ws + 96 * MB);
    ushort* xh = (ushort*)((char*)d_ws + 128 * MB);
    ushort* wqkvh = (ushort*)((char*)d_ws + 160 * MB);
    ushort* wouth = (ushort*)((char*)d_ws + 166 * MB);

    // all three converts in one launch (r8 proven)
    to_f16_all<<<2048, 256, 0, stream>>>(x, Wqkv, Wout, xh, wqkvh, wouth);

    // GEMM1: qkvh = xh @ wqkvh^T  [16384,1024]x[3072,1024]^T, f16 out
    dim3 g1(3 * DDIM / 128, M / 128);  // 24 x 128 = 3072 wgs (%8==0)
    gemm_f16<1><<<g1, 256, 0, stream>>>(xh, wqkvh, qkvh, 3 * DDIM, DDIM);

    // conv + gate -> gh (channel-pair vectorized, 256 threads)
    dim3 g2(LDIM / LCHUNK, 2, BDIM);  // 64 x 2 x 4 = 512 blocks
    conv_gate_f16<<<g2, 256, 0, stream>>>(qkvh, decay, gh);

    // GEMM2: out = gh @ wouth^T  [16384,1024]x[1024,1024]^T, f32 out
    dim3 g3(DDIM / 128, M / 128);  // 8 x 128 = 1024 wgs (%8==0)
    gemm_f16<0><<<g3, 256, 0, stream>>>(gh, wouth, d_out, DDIM, DDIM);
}

// Round 13
// 237.123 us; speedup vs baseline: 1.3955x; 1.0887x over previous
//
#include <hip/hip_runtime.h>

#define BDIM 4
#define LDIM 4096
#define DDIM 1024
#define KTAPS 128
#define LCHUNK 64

typedef __attribute__((ext_vector_type(8))) _Float16 f16x8;
typedef __attribute__((ext_vector_type(16))) float f32x16;

// ---------------------------------------------------------------------------
// fp16 helpers
// ---------------------------------------------------------------------------
__device__ __forceinline__ float f16_to_f(ushort h) {
    return (float)__builtin_bit_cast(_Float16, h);
}
__device__ __forceinline__ ushort f_to_f16(float f) {
    return __builtin_bit_cast(ushort, (_Float16)f);  // v_cvt_f16_f32, RNE
}

__device__ __forceinline__ void load_lds16(const ushort* g, ushort* l) {
    __builtin_amdgcn_global_load_lds(
        (const __attribute__((address_space(1))) void*)g,
        (__attribute__((address_space(3))) void*)l, 16, 0, 0);
}

// ---------------------------------------------------------------------------
// fused fp32 -> fp16 convert for all three inputs (one launch) — r8 proven
// ---------------------------------------------------------------------------
#define NX4 (BDIM * LDIM * DDIM / 4)        // 4194304
#define NQ4 (3 * DDIM * DDIM / 4)           // 786432
#define NO4 (DDIM * DDIM / 4)               // 262144
__global__ __launch_bounds__(256) void to_f16_all(const float* __restrict__ x,
                                                  const float* __restrict__ wq,
                                                  const float* __restrict__ wo,
                                                  ushort* __restrict__ xh,
                                                  ushort* __restrict__ wqh,
                                                  ushort* __restrict__ woh) {
    const int ntot = NX4 + NQ4 + NO4;
    for (int i = blockIdx.x * 256 + threadIdx.x; i < ntot; i += gridDim.x * 256) {
        const float* src;
        ushort* dst;
        int j = i;
        if (j < NX4) {
            src = x; dst = xh;
        } else if (j < NX4 + NQ4) {
            j -= NX4; src = wq; dst = wqh;
        } else {
            j -= NX4 + NQ4; src = wo; dst = woh;
        }
        const float4 v = *(const float4*)&src[(size_t)j * 4];
        ushort4 h;
        h.x = f_to_f16(v.x);
        h.y = f_to_f16(v.y);
        h.z = f_to_f16(v.z);
        h.w = f_to_f16(v.w);
        *(ushort4*)&dst[(size_t)j * 4] = h;
    }
}

// ---------------------------------------------------------------------------
// fp16 NT GEMM — r8 template with BK=64 (ROUND-13 parameter change):
// 128x128 tile, 4 waves, single 32KB buffer set, two __syncthreads/iter,
// NT = K/64 iters (half the barrier events of BK=32; 2x MFMA per window).
// LDS layout: [128][64] f16 per matrix; 8-octet rows, octet swizzle
// phys = logical ^ (row&7) (s-invariant since rows differ by multiples of
// 32 within a thread's staging set and 32 = 0 mod 8).
// Staging: 8 gload_lds/thread, linear dest (rule #21), pre-swizzled source.
// ks-inner loop keeps live operand regs at 4 x f16x8 to protect occupancy.
// A/B frag map: lane l -> row/col = l&31, k-octet per ks = 2*ks + (l>>5);
// C/D map (m74/m101): col = lane&31, row = (q&3)+8*(q>>2)+4*(lane>>5).
// OBF=1 -> f16 C, OBF=0 -> f32 C. XCD-aware tile swizzle.
// ---------------------------------------------------------------------------
template <int OBF>
__global__ __launch_bounds__(256) void gemm_f16(const ushort* __restrict__ A,
                                                const ushort* __restrict__ B,
                                                void* __restrict__ Cp, int ldc, int Kc) {
    __shared__ ushort As[128 * 64];
    __shared__ ushort Bs[128 * 64];

    const int tid = threadIdx.x;

    const int gx = gridDim.x;
    const int nwg = gx * gridDim.y;
    const int orig = blockIdx.y * gx + blockIdx.x;
    const int q8 = nwg >> 3;
    const int tile = (orig & 7) * q8 + (orig >> 3);
    const int m0 = (tile / gx) * 128;
    const int n0 = (tile % gx) * 128;

    // staging: thread t covers rows srow+32s (s=0..3), octet t&7;
    // source octet = (t&7) ^ (srow&7)  (same for all s: 32 == 0 mod 8)
    const int srow = tid >> 3;
    const int osrc = (tid & 7) ^ (srow & 7);

    const ushort* srcA = A + (size_t)(m0 + srow) * Kc + osrc * 8;
    const ushort* srcB = B + (size_t)(n0 + srow) * Kc + osrc * 8;

    const int lane = tid & 63;
    const int w = tid >> 6;
    const int wr = w >> 1, wc = w & 1;
    const int l31 = lane & 31;
    const int hi = lane >> 5;
    const int swz = l31 & 7;            // read-side octet swizzle (rows == l31 mod 32)
    const int arow = wr * 64 + l31;
    const int brow = wc * 64 + l31;

    f32x16 acc[2][2] = {};

    for (int kc = 0; kc < Kc; kc += 64) {
        __syncthreads();
#pragma unroll
        for (int s = 0; s < 4; ++s) {
            const size_t so = (size_t)(s * 32) * Kc + kc;
            load_lds16(srcA + so, &As[s * 2048 + tid * 8]);
            load_lds16(srcB + so, &Bs[s * 2048 + tid * 8]);
        }
        __syncthreads();

#pragma unroll
        for (int ks = 0; ks < 4; ++ks) {
            const int oph = ((2 * ks + hi) ^ swz) * 8;
            f16x8 a0 = *(const f16x8*)&As[arow * 64 + oph];
            f16x8 a1 = *(const f16x8*)&As[(arow + 32) * 64 + oph];
            f16x8 b0 = *(const f16x8*)&Bs[brow * 64 + oph];
            f16x8 b1 = *(const f16x8*)&Bs[(brow + 32) * 64 + oph];
            acc[0][0] = __builtin_amdgcn_mfma_f32_32x32x16_f16(a0, b0, acc[0][0], 0, 0, 0);
            acc[0][1] = __builtin_amdgcn_mfma_f32_32x32x16_f16(a0, b1, acc[0][1], 0, 0, 0);
            acc[1][0] = __builtin_amdgcn_mfma_f32_32x32x16_f16(a1, b0, acc[1][0], 0, 0, 0);
            acc[1][1] = __builtin_amdgcn_mfma_f32_32x32x16_f16(a1, b1, acc[1][1], 0, 0, 0);
        }
    }

#pragma unroll
    for (int rb = 0; rb < 2; ++rb)
#pragma unroll
        for (int cb = 0; cb < 2; ++cb) {
            const int colb = n0 + wc * 64 + cb * 32 + l31;
            const int rowb = m0 + wr * 64 + rb * 32 + 4 * hi;
#pragma unroll
            for (int q = 0; q < 16; ++q) {
                const int row = rowb + (q & 3) + 8 * (q >> 2);
                if (OBF) {
                    ((ushort*)Cp)[(size_t)row * ldc + colb] = f_to_f16(acc[rb][cb][q]);
                } else {
                    ((float*)Cp)[(size_t)row * ldc + colb] = acc[rb][cb][q];
                }
            }
        }
}

// ---------------------------------------------------------------------------
// conv + gate, channel-pair vectorized, ROUND-13: pure truncated IIR —
// the l-128 subtract term is dropped. decay^128 = e^-10.08 ~= 4e-5, so the
// extra tail terms contribute ~2e-5 absolute on the final output (threshold
// 4.9e-2). Removes 2 of 5 body loads per l: conv traffic 320->256MB.
// Chunk 0 (l<64 < 128 taps) remains exact; seeds unchanged.
// ---------------------------------------------------------------------------
__device__ __forceinline__ float2 up2(uint u) {
    return make_float2(f16_to_f((ushort)(u & 0xffff)), f16_to_f((ushort)(u >> 16)));
}

__global__ __launch_bounds__(256) void conv_gate_f16(const ushort* __restrict__ qkvh,
                                                     const float* __restrict__ decay,
                                                     ushort* __restrict__ gh) {
    __shared__ float sdec[KTAPS];
    if (threadIdx.x < KTAPS) sdec[threadIdx.x] = decay[threadIdx.x];
    __syncthreads();

    const int dp = blockIdx.y * 256 + threadIdx.x;  // d-pair 0..511
    const int b = blockIdx.z;
    const int l0 = blockIdx.x * LCHUNK;

    const float r = sdec[1];
    const int rsu = 3 * DDIM / 2;  // qkv row stride in uints
    const int gsu = DDIM / 2;      // gh row stride in uints

    const uint* basep = (const uint*)(qkvh + (size_t)b * LDIM * 3 * DDIM);
    const uint* qc = basep + dp;
    const uint* kc = basep + DDIM / 2 + dp;
    const uint* vc = basep + DDIM + dp;
    uint* g0 = (uint*)(gh + (size_t)b * LDIM * DDIM) + dp;

    float res0 = 0.f, res1 = 0.f;
    int lstart;

    if (l0 == 0) {
        lstart = 0;
    } else {
        // seed: res[l0] = sum_{t=0}^{min(127,l0)} decay[t] * src[l0-t]
        const int tmax = (l0 < KTAPS - 1) ? l0 : (KTAPS - 1);
#pragma unroll 4
        for (int t = 0; t <= tmax; ++t) {
            const size_t off = (size_t)(l0 - t) * rsu;
            const float2 kk = up2(kc[off]), vv = up2(vc[off]);
            res0 += sdec[t] * kk.x * vv.x;
            res1 += sdec[t] * kk.y * vv.y;
        }
        const float2 qq = up2(qc[(size_t)l0 * rsu]);
        g0[(size_t)l0 * gsu] = (uint)f_to_f16(qq.x * res0) |
                               ((uint)f_to_f16(qq.y * res1) << 16);
        lstart = l0 + 1;
    }

    for (int l = lstart; l < l0 + LCHUNK; ++l) {
        const size_t off = (size_t)l * rsu;
        const float2 kk = up2(kc[off]), vv = up2(vc[off]);
        res0 = r * res0 + kk.x * vv.x;
        res1 = r * res1 + kk.y * vv.y;
        const float2 qq = up2(qc[off]);
        g0[(size_t)l * gsu] = (uint)f_to_f16(qq.x * res0) |
                              ((uint)f_to_f16(qq.y * res1) << 16);
    }
}

// ---------------------------------------------------------------------------
// Memory plan (ws proven >= 192MB; uses 168MB):
//   ws[  0.. 96MB) qkvh  f16 [16384,3072]  GEMM1 out
//   ws[ 96..128MB) gh    f16 [16384,1024]  conv out = GEMM2 A
//   ws[128..160MB) xh    f16 [16384,1024]  GEMM1 A
//   ws[160..166MB) wqkvh f16 [3072,1024]   GEMM1 B
//   ws[166..168MB) wouth f16 [1024,1024]   GEMM2 B
// ---------------------------------------------------------------------------
extern "C" void kernel_launch(void* const* d_in, const int* in_sizes, int n_in,
                              void* d_out, int out_size, void* d_ws, size_t ws_size,
                              hipStream_t stream) {
    const float* x = (const float*)d_in[0];
    const float* Wqkv = (const float*)d_in[1];
    const float* Wout = (const float*)d_in[2];
    const float* decay = (const float*)d_in[3];

    const int M = BDIM * LDIM;  // 16384
    const size_t MB = 1024 * 1024;

    ushort* qkvh = (ushort*)d_ws;
    ushort* gh = (ushort*)((char*)d_ws + 96 * MB);
    ushort* xh = (ushort*)((char*)d_ws + 128 * MB);
    ushort* wqkvh = (ushort*)((char*)d_ws + 160 * MB);
    ushort* wouth = (ushort*)((char*)d_ws + 166 * MB);

    // all three converts in one launch
    to_f16_all<<<2048, 256, 0, stream>>>(x, Wqkv, Wout, xh, wqkvh, wouth);

    // GEMM1: qkvh = xh @ wqkvh^T  [16384,1024]x[3072,1024]^T, f16 out
    dim3 g1(3 * DDIM / 128, M / 128);  // 24 x 128 = 3072 wgs (%8==0)
    gemm_f16<1><<<g1, 256, 0, stream>>>(xh, wqkvh, qkvh, 3 * DDIM, DDIM);

    // conv + gate -> gh (channel-pair vectorized, subtract-free IIR)
    dim3 g2(LDIM / LCHUNK, 2, BDIM);  // 64 x 2 x 4 = 512 blocks
    conv_gate_f16<<<g2, 256, 0, stream>>>(qkvh, decay, gh);

    // GEMM2: out = gh @ wouth^T  [16384,1024]x[1024,1024]^T, f32 out
    dim3 g3(DDIM / 128, M / 128);  // 8 x 128 = 1024 wgs (%8==0)
    gemm_f16<0><<<g3, 256, 0, stream>>>(gh, wouth, d_out, DDIM, DDIM);
}